// Round 1
// baseline (898.377 us; speedup 1.0000x reference)
//
#include <hip/hip_runtime.h>
#include <math.h>

#define V_NODES 100000
#define E_EDGES 800000
#define HEADS 4
#define FH 32
#define D 128
#define LEAK 0.2f
#define NB 8

// ---------------- Kernel 1: fused QKV projection ----------------
// C[V,384] = h[V,128] @ [Wq|Wk|Wv] + [bq|bk|bv], written as 3 separate [V,128] buffers.
// 384 threads/block, NB=8 nodes per block. h staged transposed in LDS so the
// k-loop reads a broadcast address (conflict-free) and W reads are coalesced.
__global__ __launch_bounds__(384) void qkv_kernel(
    const float* __restrict__ h,
    const float* __restrict__ Wq, const float* __restrict__ bq,
    const float* __restrict__ Wk, const float* __restrict__ bk,
    const float* __restrict__ Wv, const float* __restrict__ bv,
    float* __restrict__ Q, float* __restrict__ K, float* __restrict__ Vv)
{
    __shared__ float hsh[D][NB];   // [k][n] transposed
    const int tid  = threadIdx.x;
    const int base = blockIdx.x * NB;

    for (int idx = tid; idx < NB * D; idx += 384) {
        int n = idx >> 7, k = idx & 127;
        hsh[k][n] = h[(long)(base + n) * D + k];
    }
    __syncthreads();

    const int wsel = tid >> 7;      // 0=Q,1=K,2=V  (wave-uniform: 2 waves per sel)
    const int col  = tid & 127;
    const float* W = (wsel == 0) ? Wq : (wsel == 1) ? Wk : Wv;
    const float* b = (wsel == 0) ? bq : (wsel == 1) ? bk : bv;
    float* O       = (wsel == 0) ? Q  : (wsel == 1) ? K  : Vv;

    float acc[NB];
#pragma unroll
    for (int n = 0; n < NB; n++) acc[n] = 0.f;

    for (int k = 0; k < D; k++) {
        float w = W[k * D + col];
#pragma unroll
        for (int n = 0; n < NB; n++) acc[n] += hsh[k][n] * w;
    }

    float bias = b[col];
#pragma unroll
    for (int n = 0; n < NB; n++) O[(long)(base + n) * D + col] = acc[n] + bias;
}

// ---------------- Kernel 2: per-edge multi-head scores + softmax denominator ----------------
// One thread per edge; computes 4 head scores, exp, stores attn_exp[e][4],
// atomically accumulates deg[tgt][4].
__global__ __launch_bounds__(256) void score_kernel(
    const int* __restrict__ src, const int* __restrict__ tgt,
    const float* __restrict__ ew,
    const float* __restrict__ Q, const float* __restrict__ K,
    const float* __restrict__ We, const float* __restrict__ be,
    float* __restrict__ attn_exp, float* __restrict__ deg)
{
    int e = blockIdx.x * 256 + threadIdx.x;
    if (e >= E_EDGES) return;
    int s = src[e], t = tgt[e];
    float w = ew[e];
    const float4* q4 = (const float4*)(Q + (long)s * D);
    const float4* k4 = (const float4*)(K + (long)t * D);

    float outv[HEADS];
#pragma unroll
    for (int hh = 0; hh < HEADS; hh++) {
        float dot = 0.f;
#pragma unroll
        for (int i = 0; i < 8; i++) {
            float4 a = q4[hh * 8 + i];
            float4 b = k4[hh * 8 + i];
            dot += a.x * b.x + a.y * b.y + a.z * b.z + a.w * b.w;
        }
        float bias = w * We[hh] + be[hh];
        bias = (bias > 0.f) ? bias : LEAK * bias;
        float sc = dot * 0.17677669529663687f + bias;  // 1/sqrt(32)
        outv[hh] = __expf(sc);
    }
    *((float4*)(attn_exp + (long)e * 4)) = make_float4(outv[0], outv[1], outv[2], outv[3]);
#pragma unroll
    for (int hh = 0; hh < HEADS; hh++) atomicAdd(&deg[t * 4 + hh], outv[hh]);
}

// ---------------- Kernel 3: normalize + weighted message scatter ----------------
// One thread per (edge, channel). Skips omega==0 edges (1/3 of them).
__global__ __launch_bounds__(256) void agg_kernel(
    const int* __restrict__ src, const int* __restrict__ tgt,
    const float* __restrict__ ew,
    const float* __restrict__ Vv, const float* __restrict__ attn_exp,
    const float* __restrict__ deg, float* __restrict__ out)
{
    long gid = (long)blockIdx.x * 256 + threadIdx.x;
    int e = (int)(gid >> 7);
    int c = (int)(gid & 127);
    float w = ew[e];
    if (w == 0.f) return;
    int t = tgt[e];
    int hh = c >> 5;
    float a = attn_exp[(long)e * 4 + hh] / (deg[t * 4 + hh] + 1e-16f) * w;
    float m = a * Vv[(long)src[e] * D + c];
    atomicAdd(&out[(long)t * D + c], m);
}

// ---------------- Kernel 4: out = LeakyReLU(LayerNorm(agg @ Wo + bo + h)) ----------------
// agg lives in d_out (read, then overwritten). 128 threads/block, NB nodes/block.
__global__ __launch_bounds__(128) void out_kernel(
    const float* __restrict__ h, const float* __restrict__ Wo,
    const float* __restrict__ bo, const float* __restrict__ gamma,
    const float* __restrict__ beta, float* __restrict__ out)
{
    __shared__ float ash[D][NB];    // transposed agg tile [k][n]
    __shared__ float red[2][NB][2]; // per-wave partial (sum, sumsq)
    const int tid  = threadIdx.x;
    const int base = blockIdx.x * NB;
    const int wave = tid >> 6, lane = tid & 63;

#pragma unroll
    for (int n = 0; n < NB; n++) ash[tid][n] = out[(long)(base + n) * D + tid];
    __syncthreads();

    float acc[NB];
#pragma unroll
    for (int n = 0; n < NB; n++) acc[n] = 0.f;
    for (int k = 0; k < D; k++) {
        float w = Wo[k * D + tid];
#pragma unroll
        for (int n = 0; n < NB; n++) acc[n] += ash[k][n] * w;
    }

    float bb = bo[tid];
    float v[NB];
#pragma unroll
    for (int n = 0; n < NB; n++) {
        v[n] = acc[n] + bb + h[(long)(base + n) * D + tid];
        float s = v[n], q = v[n] * v[n];
#pragma unroll
        for (int off = 32; off; off >>= 1) {
            s += __shfl_xor(s, off);
            q += __shfl_xor(q, off);
        }
        if (lane == 0) { red[wave][n][0] = s; red[wave][n][1] = q; }
    }
    __syncthreads();

    float g = gamma[tid], bt = beta[tid];
#pragma unroll
    for (int n = 0; n < NB; n++) {
        float s  = red[0][n][0] + red[1][n][0];
        float q  = red[0][n][1] + red[1][n][1];
        float mu = s * (1.f / 128.f);
        float var = q * (1.f / 128.f) - mu * mu;
        float rstd = rsqrtf(var + 1e-5f);
        float y = (v[n] - mu) * rstd * g + bt;
        out[(long)(base + n) * D + tid] = (y > 0.f) ? y : LEAK * y;
    }
}

extern "C" void kernel_launch(void* const* d_in, const int* in_sizes, int n_in,
                              void* d_out, int out_size, void* d_ws, size_t ws_size,
                              hipStream_t stream)
{
    const float* h     = (const float*)d_in[0];
    const int*   ei    = (const int*)d_in[1];
    const float* ew    = (const float*)d_in[2];
    const float* Wq    = (const float*)d_in[3];
    const float* bq    = (const float*)d_in[4];
    const float* Wk    = (const float*)d_in[5];
    const float* bk    = (const float*)d_in[6];
    const float* Wv    = (const float*)d_in[7];
    const float* bv    = (const float*)d_in[8];
    const float* Wo    = (const float*)d_in[9];
    const float* bo    = (const float*)d_in[10];
    const float* We    = (const float*)d_in[11];
    const float* be    = (const float*)d_in[12];
    const float* gamma = (const float*)d_in[13];
    const float* beta  = (const float*)d_in[14];
    float* out = (float*)d_out;

    float* Q        = (float*)d_ws;                    // V*128
    float* K        = Q  + (size_t)V_NODES * D;        // V*128
    float* Vv       = K  + (size_t)V_NODES * D;        // V*128
    float* attn_exp = Vv + (size_t)V_NODES * D;        // E*4
    float* deg      = attn_exp + (size_t)E_EDGES * 4;  // V*4

    const int* srcp = ei;
    const int* tgtp = ei + E_EDGES;

    // out doubles as the aggregation buffer; both it and deg need zeros
    hipMemsetAsync(out, 0, (size_t)V_NODES * D * sizeof(float), stream);
    hipMemsetAsync(deg, 0, (size_t)V_NODES * HEADS * sizeof(float), stream);

    qkv_kernel<<<V_NODES / NB, 384, 0, stream>>>(h, Wq, bq, Wk, bk, Wv, bv, Q, K, Vv);
    score_kernel<<<E_EDGES / 256, 256, 0, stream>>>(srcp, tgtp, ew, Q, K, We, be, attn_exp, deg);
    agg_kernel<<<(int)((long)E_EDGES * D / 256), 256, 0, stream>>>(srcp, tgtp, ew, Vv, attn_exp, deg, out);
    out_kernel<<<V_NODES / NB, 128, 0, stream>>>(h, Wo, bo, gamma, beta, out);
}